// Round 28
// baseline (634.196 us; speedup 1.0000x reference)
//
#include <hip/hip_runtime.h>
#include <hip/hip_bf16.h>
#include <math.h>

#define BB 256
#define SS 400
#define HH 512
#define EMBD 1024
#define VV 50257
#define VE 50357   // V + EXTRA
#define O_HID  12891392   // 256*50357
#define O_ATT  13022464   // O_HID + 256*512
#define O_SIG  13124864   // O_ATT + 400*256

typedef __attribute__((ext_vector_type(8))) short s8v;    // 8 bf16 (4 VGPR) MFMA A/B frag
typedef __attribute__((ext_vector_type(4))) float f4v;    // MFMA C/D frag

__device__ __forceinline__ float sigmoidf(float x) { return 1.f / (1.f + expf(-x)); }
__device__ __forceinline__ float geluf(float x) { return 0.5f * x * (1.f + erff(x * 0.70710678118654752f)); }

// round-to-nearest-even bf16 pack of TWO floats (r26/r27)
__device__ __forceinline__ unsigned rne2_pack(float x0, float x1) {
  unsigned u0 = __float_as_uint(x0), u1 = __float_as_uint(x1);
  unsigned r0 = (u0 + 0x7FFFu + ((u0 >> 16) & 1u)) >> 16;
  unsigned r1 = (u1 + 0x7FFFu + ((u1 >> 16) & 1u)) & 0xFFFF0000u;
  return r0 | r1;
}

// monotonic float<->unsigned key for atomicMax on floats (init key = 0 == -inf)
__device__ __forceinline__ unsigned fkey(float x) {
  unsigned u = __float_as_uint(x);
  return (u & 0x80000000u) ? ~u : (u | 0x80000000u);
}
__device__ __forceinline__ float fdecode(unsigned key) {
  unsigned u = (key & 0x80000000u) ? (key & 0x7FFFFFFFu) : ~key;
  return __uint_as_float(u);
}

// ---------------- generic NT GEMM: C[m,n] = act(sum_k A[m,k]*W[n,k] + bias[n]) ----------------
template<int ACT>
__global__ __launch_bounds__(256) void gemm_nt(const float* __restrict__ A, int lda,
                                               const float* __restrict__ W, int ldw,
                                               const float* __restrict__ bias,
                                               float* __restrict__ C, int ldc,
                                               int N, int K) {
  __shared__ __align__(16) float As[16][68];
  __shared__ __align__(16) float Ws[16][68];
  const int tid = threadIdx.x;
  const int m0 = blockIdx.x * 64, n0 = blockIdx.y * 64;
  const int tx = tid & 15, ty = tid >> 4;
  const int lr = tid >> 2;
  const int lk = (tid & 3) * 4;
  float acc[4][4] = {};
  for (int k0 = 0; k0 < K; k0 += 16) {
    float4 a4, w4;
    a4 = *(const float4*)(A + (size_t)(m0 + lr) * lda + k0 + lk);
    int wrow = n0 + lr;
    if (wrow < N) w4 = *(const float4*)(W + (size_t)wrow * ldw + k0 + lk);
    else          w4 = make_float4(0.f, 0.f, 0.f, 0.f);
    __syncthreads();
    As[lk + 0][lr] = a4.x; As[lk + 1][lr] = a4.y; As[lk + 2][lr] = a4.z; As[lk + 3][lr] = a4.w;
    Ws[lk + 0][lr] = w4.x; Ws[lk + 1][lr] = w4.y; Ws[lk + 2][lr] = w4.z; Ws[lk + 3][lr] = w4.w;
    __syncthreads();
#pragma unroll
    for (int k = 0; k < 16; ++k) {
      float4 av = *(const float4*)&As[k][ty * 4];
      float4 wv = *(const float4*)&Ws[k][tx * 4];
      float am[4] = {av.x, av.y, av.z, av.w};
      float wn[4] = {wv.x, wv.y, wv.z, wv.w};
#pragma unroll
      for (int i = 0; i < 4; ++i)
#pragma unroll
        for (int j = 0; j < 4; ++j) acc[i][j] += am[i] * wn[j];
    }
  }
#pragma unroll
  for (int i = 0; i < 4; ++i) {
    int row = m0 + ty * 4 + i;
#pragma unroll
    for (int j = 0; j < 4; ++j) {
      int col = n0 + tx * 4 + j;
      if (col < N) {
        float val = acc[i][j] + bias[col];
        if (ACT == 1) val = geluf(val);
        C[(size_t)row * ldc + col] = val;
      }
    }
  }
}

// ---------------- merged GRU input+hidden GEMMs: one launch, 192 concurrent blocks ----------------
__global__ __launch_bounds__(256) void gru_gemms(const float* __restrict__ input_step,
                                                 const float* __restrict__ last_hidden,
                                                 const float* __restrict__ W_ih,
                                                 const float* __restrict__ W_hh,
                                                 const float* __restrict__ b_ih,
                                                 const float* __restrict__ b_hh,
                                                 float* __restrict__ gi, float* __restrict__ gh) {
  __shared__ __align__(16) float As[16][68];
  __shared__ __align__(16) float Ws[16][68];
  const bool isGi = blockIdx.y < 24;
  const float* A = isGi ? input_step : last_hidden;
  const float* W = isGi ? W_ih : W_hh;
  const float* bias = isGi ? b_ih : b_hh;
  float* C = isGi ? gi : gh;
  const int lda = isGi ? 1024 : 512;
  const int K = isGi ? 1024 : 512;
  const int n0 = (isGi ? blockIdx.y : blockIdx.y - 24) * 64;
  const int m0 = blockIdx.x * 64;
  const int tid = threadIdx.x;
  const int tx = tid & 15, ty = tid >> 4;
  const int lr = tid >> 2;
  const int lk = (tid & 3) * 4;
  float acc[4][4] = {};
  for (int k0 = 0; k0 < K; k0 += 16) {
    float4 a4 = *(const float4*)(A + (size_t)(m0 + lr) * lda + k0 + lk);
    float4 w4 = *(const float4*)(W + (size_t)(n0 + lr) * lda + k0 + lk);   // ldw == lda here
    __syncthreads();
    As[lk + 0][lr] = a4.x; As[lk + 1][lr] = a4.y; As[lk + 2][lr] = a4.z; As[lk + 3][lr] = a4.w;
    Ws[lk + 0][lr] = w4.x; Ws[lk + 1][lr] = w4.y; Ws[lk + 2][lr] = w4.z; Ws[lk + 3][lr] = w4.w;
    __syncthreads();
#pragma unroll
    for (int k = 0; k < 16; ++k) {
      float4 av = *(const float4*)&As[k][ty * 4];
      float4 wv = *(const float4*)&Ws[k][tx * 4];
      float am[4] = {av.x, av.y, av.z, av.w};
      float wn[4] = {wv.x, wv.y, wv.z, wv.w};
#pragma unroll
      for (int i = 0; i < 4; ++i)
#pragma unroll
        for (int j = 0; j < 4; ++j) acc[i][j] += am[i] * wn[j];
    }
  }
#pragma unroll
  for (int i = 0; i < 4; ++i) {
    int row = m0 + ty * 4 + i;
#pragma unroll
    for (int j = 0; j < 4; ++j) {
      int col = n0 + tx * 4 + j;
      C[(size_t)row * 1536 + col] = acc[i][j] + bias[col];
    }
  }
}

// ---------------- GRU gate combine ----------------
__global__ __launch_bounds__(256) void gru_combine(const float* __restrict__ gi, const float* __restrict__ gh,
                                                   const float* __restrict__ hprev,
                                                   float* __restrict__ rnn, float* __restrict__ hid_out,
                                                   float* __restrict__ cin) {
  int idx = blockIdx.x * 256 + threadIdx.x;
  int b = idx >> 9, j = idx & 511;
  const float* gib = gi + (size_t)b * 1536;
  const float* ghb = gh + (size_t)b * 1536;
  float r = sigmoidf(gib[j] + ghb[j]);
  float z = sigmoidf(gib[512 + j] + ghb[512 + j]);
  float n = tanhf(gib[1024 + j] + r * ghb[1024 + j]);
  float h = hprev[idx];
  float o = (1.f - z) * n + z * h;
  rnn[idx] = o;
  hid_out[idx] = o;
  cin[(size_t)b * 1024 + j] = o;
}

// ---------------- pack a [rows][K=512] fp32 operand into MFMA-fragment-ordered single bf16 (RNE) ----
__global__ __launch_bounds__(256) void pack_rne(const float* __restrict__ src, int ld, int col0, int rows,
                                                unsigned short* __restrict__ d) {
  int idx = blockIdx.x * 256 + threadIdx.x;   // = (jb*16 + kb)*64 + l
  int l = idx & 63;
  int kb = (idx >> 6) & 15;
  int jb = idx >> 10;
  int j = jb * 16 + (l & 15);
  int k0 = kb * 32 + (l >> 4) * 8;
  float4 x0 = make_float4(0.f, 0.f, 0.f, 0.f), x1 = x0;
  if (j < rows) {
    const float* p = src + (size_t)j * ld + col0 + k0;
    x0 = *(const float4*)p;
    x1 = *(const float4*)(p + 4);
  }
  uint4 p = make_uint4(rne2_pack(x0.x, x0.y), rne2_pack(x0.z, x0.w),
                       rne2_pack(x1.x, x1.y), rne2_pack(x1.z, x1.w));
  *(uint4*)(d + (size_t)idx * 8) = p;
}

// ---------------- MFMA single-bf16 energy GEMM, barrier-free direct-load (r28) ------------------
// r27's counters showed latency/barrier serialization (no pipe >33%): the LDS A-staging barrier
// convoyed all waves on each K-step's HBM load. With cheap RNE packing, each lane now loads its
// own A fragment directly (row rt*16+l16, k-slice g*8: 2x float4, 128B-line coalesced) and packs
// in-register. 4x A redundancy across waves is L2-absorbed. NO __syncthreads in the K loop.
__global__ __launch_bounds__(256, 2) void attn_mfma(const float* __restrict__ enc,
                                                    const unsigned short* __restrict__ BP,
                                                    const float* __restrict__ hW,
                                                    const float* __restrict__ v,
                                                    float* __restrict__ scores) {
  __shared__ float sredf[64][4];   // epilogue reduce only (1 KB)

  const int tid = threadIdx.x;
  const int R0 = blockIdx.x * 64;
  const int jhalf = blockIdx.y;      // 0 or 1
  const int lane = tid & 63;
  const int w = tid >> 6;            // wave 0..3 -> 64-col group within the 256-col half
  const int jbBase = jhalf * 16 + w * 4;   // fragment-blocks of 16 cols
  const int g = lane >> 4;           // k-chunk 0..3
  const int l16 = lane & 15;

  // per-lane A base: row R0 + l16 (+ rt*16), k-offset g*8
  const float* a0 = enc + (size_t)(R0 + l16) * 512 + g * 8;
  const unsigned short* b0p = BP + lane * 8;   // fragment-packed: lane-contiguous

  f4v acc[4][4];
#pragma unroll
  for (int rt = 0; rt < 4; ++rt)
#pragma unroll
    for (int ct = 0; ct < 4; ++ct) acc[rt][ct] = (f4v){0.f, 0.f, 0.f, 0.f};

  s8v BH[4];
#pragma unroll
  for (int ct = 0; ct < 4; ++ct)
    BH[ct] = *(const s8v*)(b0p + ((jbBase + ct) * 16 + 0) * 512);

  // ---- main K loop: 16 steps of 32; per-lane direct loads, no barriers ----
  for (int t = 0; t < 16; ++t) {
    const int k0 = t * 32;
    // load + pack this step's 4 A fragments (rt-major; 8192 floats = 16 rows per rt block)
    s8v af[4];
#pragma unroll
    for (int rt = 0; rt < 4; ++rt) {
      const float* ap = a0 + k0 + rt * 8192;
      float4 x0 = *(const float4*)(ap);
      float4 x1 = *(const float4*)(ap + 4);
      uint4 p = make_uint4(rne2_pack(x0.x, x0.y), rne2_pack(x0.z, x0.w),
                           rne2_pack(x1.x, x1.y), rne2_pack(x1.z, x1.w));
      af[rt] = *(s8v*)&p;
    }
#pragma unroll
    for (int rt = 0; rt < 4; ++rt)
#pragma unroll
      for (int ct = 0; ct < 4; ++ct)
        acc[rt][ct] = __builtin_amdgcn_mfma_f32_16x16x32_bf16(af[rt], BH[ct], acc[rt][ct], 0, 0, 0);
    if (t < 15) {
#pragma unroll
      for (int ct = 0; ct < 4; ++ct)
        BH[ct] = *(const s8v*)(b0p + ((jbBase + ct) * 16 + (t + 1)) * 512);
    }
  }

  // ---- epilogue: sp += tanh(acc + hW) * v over this wave's 64 cols ----
  float sp[4][4] = {};
#pragma unroll
  for (int ct = 0; ct < 4; ++ct) {
    int j = jhalf * 256 + w * 64 + ct * 16 + l16;
    float vj = v[j];
    const float* hWj = hW + j;
#pragma unroll
    for (int rt = 0; rt < 4; ++rt) {
#pragma unroll
      for (int q = 0; q < 4; ++q) {
        int rl = rt * 16 + g * 4 + q;
        int b = (R0 + rl) & 255;
        float e = acc[rt][ct][q] + hWj[(size_t)b * 512];
        sp[rt][q] += tanhf(e) * vj;
      }
    }
  }

  // ---- reduce: sum over 16 lanes (cols) then over 4 waves; atomicAdd partial ----
#pragma unroll
  for (int rt = 0; rt < 4; ++rt)
#pragma unroll
    for (int q = 0; q < 4; ++q) {
      float s = sp[rt][q];
      s += __shfl_xor(s, 1); s += __shfl_xor(s, 2);
      s += __shfl_xor(s, 4); s += __shfl_xor(s, 8);
      if (l16 == 0) sredf[rt * 16 + g * 4 + q][w] = s;
    }
  __syncthreads();
  if (tid < 64) {
    float s = sredf[tid][0] + sredf[tid][1] + sredf[tid][2] + sredf[tid][3];
    int r = R0 + tid;
    int b = r & 255, si = r >> 8;
    atomicAdd(scores + b * 400 + si, s);
  }
}

// ---------------- MFMA single-bf16 logits GEMM + per-row max (atomicMax key) ----------------
// r26 proven version.
__global__ __launch_bounds__(256, 2) void logits_mfma(const float* __restrict__ A,
                                                      const float* __restrict__ W,
                                                      const float* __restrict__ bias,
                                                      float* __restrict__ out,
                                                      unsigned* __restrict__ rowmK) {
  __shared__ __align__(16) unsigned short AL[2 * 4 * 66 * 8];

  const int tid = threadIdx.x;
  const int R0 = blockIdx.x * 64;
  const int C0 = blockIdx.y * 256;
  const int lane = tid & 63;
  const int w = tid >> 6;
  const int g = lane >> 4;
  const int l16 = lane & 15;

  const int ar = tid >> 2;
  const int akc = tid & 3;
  const float* aptr = A + (size_t)(R0 + ar) * 512 + akc * 8;

  int jc[4]; bool jok[4];
#pragma unroll
  for (int ct = 0; ct < 4; ++ct) {
    jc[ct] = C0 + w * 64 + ct * 16 + l16;
    jok[ct] = jc[ct] < VV;
  }

  f4v acc[4][4];
#pragma unroll
  for (int rt = 0; rt < 4; ++rt)
#pragma unroll
    for (int ct = 0; ct < 4; ++ct) acc[rt][ct] = (f4v){0.f, 0.f, 0.f, 0.f};

  // prologue: stage A k-tile 0 (single bf16, RNE)
  {
    float4 pa0 = *(const float4*)(aptr);
    float4 pa1 = *(const float4*)(aptr + 4);
    uint4 p = make_uint4(rne2_pack(pa0.x, pa0.y), rne2_pack(pa0.z, pa0.w),
                         rne2_pack(pa1.x, pa1.y), rne2_pack(pa1.z, pa1.w));
    *(uint4*)&AL[(akc * 66 + ar) * 8] = p;
  }
  __syncthreads();

#pragma unroll 2
  for (int t = 0; t < 16; ++t) {
    const int k0 = t * 32;
    // B(t) load + RNE pack (head of step, r24 order)
    s8v Bf[4];
#pragma unroll
    for (int ct = 0; ct < 4; ++ct) {
      const float* wp = W + (size_t)(jok[ct] ? jc[ct] : 0) * 512 + k0 + g * 8;
      float4 b0 = *(const float4*)wp;
      float4 b1 = *(const float4*)(wp + 4);
      if (!jok[ct]) { b0 = make_float4(0.f, 0.f, 0.f, 0.f); b1 = b0; }
      uint4 pb = make_uint4(rne2_pack(b0.x, b0.y), rne2_pack(b0.z, b0.w),
                            rne2_pack(b1.x, b1.y), rne2_pack(b1.z, b1.w));
      Bf[ct] = *(s8v*)&pb;
    }
    // A(t+1) prefetch issue
    float4 pa0, pa1;
    if (t < 15) {
      pa0 = *(const float4*)(aptr + k0 + 32);
      pa1 = *(const float4*)(aptr + k0 + 36);
    }
    const int rb = ((t & 1) * 4 + g) * 66 + l16;
#pragma unroll
    for (int rt = 0; rt < 4; ++rt) {
      s8v a = *(const s8v*)&AL[(rb + rt * 16) * 8];
#pragma unroll
      for (int ct = 0; ct < 4; ++ct)
        acc[rt][ct] = __builtin_amdgcn_mfma_f32_16x16x32_bf16(a, Bf[ct], acc[rt][ct], 0, 0, 0);
    }
    // A(t+1) pack + write
    if (t < 15) {
      uint4 p = make_uint4(rne2_pack(pa0.x, pa0.y), rne2_pack(pa0.z, pa0.w),
                           rne2_pack(pa1.x, pa1.y), rne2_pack(pa1.z, pa1.w));
      *(uint4*)&AL[((((t + 1) & 1) * 4 + akc) * 66 + ar) * 8] = p;
    }
    __syncthreads();
  }

  // epilogue: bias + store (cols < VV only) + per-row max tracking
  float rmax[4][4];
#pragma unroll
  for (int rt = 0; rt < 4; ++rt)
#pragma unroll
    for (int q = 0; q < 4; ++q) rmax[rt][q] = -3e38f;
#pragma unroll
  for (int ct = 0; ct < 4; ++ct) {
    if (!jok[ct]) continue;
    float bj = bias[jc[ct]];
#pragma unroll
    for (int rt = 0; rt < 4; ++rt) {
      int row = R0 + rt * 16 + g * 4;
#pragma unroll
      for (int q = 0; q < 4; ++q) {
        float val = acc[rt][ct][q] + bj;
        out[(size_t)(row + q) * VE + jc[ct]] = val;
        rmax[rt][q] = fmaxf(rmax[rt][q], val);
      }
    }
  }
  // reduce row max: over 16 lanes (cols) then over 4 waves; atomicMax key
  float* redm = (float*)AL;  // [64][4]
#pragma unroll
  for (int rt = 0; rt < 4; ++rt)
#pragma unroll
    for (int q = 0; q < 4; ++q) {
      float mx = rmax[rt][q];
      mx = fmaxf(mx, __shfl_xor(mx, 1)); mx = fmaxf(mx, __shfl_xor(mx, 2));
      mx = fmaxf(mx, __shfl_xor(mx, 4)); mx = fmaxf(mx, __shfl_xor(mx, 8));
      if (l16 == 0) redm[(rt * 16 + g * 4 + q) * 4 + w] = mx;
    }
  __syncthreads();
  if (tid < 64) {
    float mx = fmaxf(fmaxf(redm[tid * 4 + 0], redm[tid * 4 + 1]),
                     fmaxf(redm[tid * 4 + 2], redm[tid * 4 + 3]));
    if (mx > -2e38f) atomicMax(rowmK + R0 + tid, fkey(mx));
  }
}

// ---------------- row softmax over S (applies mask), write [B,S] + transposed [S,B] ----------------
__global__ __launch_bounds__(256) void softmax_k(const float* __restrict__ scores,
                                                 const float* __restrict__ masks,
                                                 float* __restrict__ attnw, float* __restrict__ attnT) {
  int b = blockIdx.x, tid = threadIdx.x;
  __shared__ float red[4];
  float m = -3e38f;
  for (int s = tid; s < 400; s += 256) {
    float sc = (masks[b * 400 + s] > 0.f) ? scores[b * 400 + s] : -1e18f;
    m = fmaxf(m, sc);
  }
#pragma unroll
  for (int o = 32; o; o >>= 1) m = fmaxf(m, __shfl_xor(m, o));
  if ((tid & 63) == 0) red[tid >> 6] = m;
  __syncthreads();
  m = fmaxf(fmaxf(red[0], red[1]), fmaxf(red[2], red[3]));
  __syncthreads();
  float z = 0.f;
  for (int s = tid; s < 400; s += 256) {
    float sc = (masks[b * 400 + s] > 0.f) ? scores[b * 400 + s] : -1e18f;
    z += expf(sc - m);
  }
#pragma unroll
  for (int o = 32; o; o >>= 1) z += __shfl_xor(z, o);
  if ((tid & 63) == 0) red[tid >> 6] = z;
  __syncthreads();
  z = red[0] + red[1] + red[2] + red[3];
  float inv = 1.f / z;
  for (int s = tid; s < 400; s += 256) {
    float sc = (masks[b * 400 + s] > 0.f) ? scores[b * 400 + s] : -1e18f;
    float w = expf(sc - m) * inv;
    attnw[b * 400 + s] = w;
    attnT[s * 256 + b] = w;
  }
}

// ---------------- fused: context + pgen (1024 thr; ctx via 4-way s-split + LDS reduce) ----------
__global__ __launch_bounds__(1024) void context_pgen_k(const float* __restrict__ enc,
                                                       const float* __restrict__ attnw,
                                                       const float* __restrict__ hprev,
                                                       const float* __restrict__ emb,
                                                       const float* __restrict__ pW,
                                                       const float* __restrict__ pb,
                                                       float* __restrict__ ctx, float* __restrict__ cin,
                                                       float* __restrict__ pgen) {
  int b = blockIdx.x, tid = threadIdx.x;
  __shared__ float w[400];
  __shared__ float part[4][512];
  __shared__ float red[16];
  for (int s = tid; s < 400; s += 1024) w[s] = attnw[b * 400 + s];
  __syncthreads();
  const int h = (tid & 255) * 2;
  const int sq = tid >> 8;            // s-quarter 0..3
  const float* p = enc + (size_t)b * 512 + h;
  float cx = 0.f, cy = 0.f;
  const int s0 = sq * 100;
#pragma unroll 4
  for (int s = s0; s < s0 + 100; ++s) {
    float2 e = *(const float2*)(p + (size_t)s * 131072);
    cx += w[s] * e.x; cy += w[s] * e.y;
  }
  part[sq][h] = cx; part[sq][h + 1] = cy;
  __syncthreads();
  float vsum = 0.f;
  if (tid < 512) {
    vsum = part[0][tid] + part[1][tid] + part[2][tid] + part[3][tid];
    ctx[(size_t)b * 512 + tid] = vsum;
    cin[(size_t)b * 1024 + 512 + tid] = vsum;
  }
  __syncthreads();
  if (tid < 512) part[0][tid] = vsum;   // ctx snapshot for pgen dot
  __syncthreads();
  // pgen dot over [hprev(512) | ctx(512) | emb(1024)]
  float acc = 0.f;
#pragma unroll
  for (int kk = 0; kk < 2; ++kk) {
    int k = tid + kk * 1024;
    float x = (k < 512) ? hprev[(size_t)b * 512 + k]
            : (k < 1024) ? part[0][k - 512]
            : emb[(size_t)b * 1024 + k - 1024];
    acc += x * pW[k];
  }
#pragma unroll
  for (int o = 32; o; o >>= 1) acc += __shfl_xor(acc, o);
  if ((tid & 63) == 0) red[tid >> 6] = acc;
  __syncthreads();
  if (tid == 0) {
    float d = pb[0];
#pragma unroll
    for (int i = 0; i < 16; ++i) d += red[i];
    pgen[b] = sigmoidf(geluf(d));
  }
}

// ---------------- sig_hid = rnn . sig_W + b ----------------
__global__ void sig_k(const float* __restrict__ rnn, const float* __restrict__ sW,
                      const float* __restrict__ sb, float* __restrict__ outp) {
  int b = blockIdx.x, tid = threadIdx.x;
  float acc = 0.f;
  for (int k = tid; k < 512; k += 64) acc += rnn[(size_t)b * 512 + k] * sW[k];
#pragma unroll
  for (int o = 32; o; o >>= 1) acc += __shfl_xor(acc, o);
  if (tid == 0) outp[b] = acc + sb[0];
}

// ---------------- fused finale: exp+Z -> scatter -> log transform (analytic logT) --------------
// Post-scatter row sum is analytically 1: coef*sum(e) = pg, sum(attnD) = 1-pg.
// -> logT = log(1 + VE*1e-5) constant; the 51.5MB re-read summation pass is DELETED (r24).
__global__ __launch_bounds__(1024) void finale_k(float* __restrict__ out,
                                                 const float* __restrict__ pgen,
                                                 const unsigned* __restrict__ rowmK,
                                                 const int* __restrict__ ebev,
                                                 const float* __restrict__ attnw) {
  const int b = blockIdx.x, tid = threadIdx.x;
  float* row = out + (size_t)b * VE;
  __shared__ float red[16];
  __shared__ float shZ;
  const float m = fdecode(rowmK[b]);
  const float pg = pgen[b];
  // phase 1: e = exp(x - m) for j < VV, 0 elsewhere; write e; accumulate Z
  float z = 0.f;
  for (int j = tid * 4; j < 50356; j += 4096) {
    float4 x = *(const float4*)(row + j);
    float4 e;
    e.x = (j + 0 < VV) ? expf(x.x - m) : 0.f;
    e.y = (j + 1 < VV) ? expf(x.y - m) : 0.f;
    e.z = (j + 2 < VV) ? expf(x.z - m) : 0.f;
    e.w = (j + 3 < VV) ? expf(x.w - m) : 0.f;
    z += e.x + e.y + e.z + e.w;
    *(float4*)(row + j) = e;
  }
  if (tid == 0) row[50356] = 0.f;
#pragma unroll
  for (int o = 32; o; o >>= 1) z += __shfl_xor(z, o);
  if ((tid & 63) == 0) red[tid >> 6] = z;
  __syncthreads();
  if (tid == 0) {
    float t = 0.f;
#pragma unroll
    for (int i = 0; i < 16; ++i) t += red[i];
    shZ = t;
  }
  __syncthreads();
  const float coef = pg / shZ;
  // phase 2: scatter attnD/coef into own row (uncontended atomics)
  if (tid < 400) {
    int idx = ebev[tid * 256 + b];
    float wv = (1.f - pg) * attnw[b * 400 + tid] / coef;
    atomicAdd(row + idx, wv);
  }
  __syncthreads();
  // phase 3: final = log(coef*e' + 1e-5) - logT, with analytic logT (sum == 1 by construction)
  const float logT = logf(1.0f + (float)VE * 1e-5f);
  volatile const float* vrow = row;
  for (int j = tid; j < VE; j += 1024) {
    float e = vrow[j];
    row[j] = logf(coef * e + 1e-5f) - logT;
  }
}

extern "C" void kernel_launch(void* const* d_in, const int* in_sizes, int n_in,
                              void* d_out, int out_size, void* d_ws, size_t ws_size,
                              hipStream_t stream) {
  const float* input_step = (const float*)d_in[0];
  const float* last_hidden = (const float*)d_in[1];
  const float* enc = (const float*)d_in[2];
  const int*   ebev = (const int*)d_in[3];
  const float* masks = (const float*)d_in[5];
  const float* W_ih = (const float*)d_in[6];
  const float* W_hh = (const float*)d_in[7];
  const float* b_ih = (const float*)d_in[8];
  const float* b_hh = (const float*)d_in[9];
  const float* attn_W = (const float*)d_in[10];
  const float* attn_b = (const float*)d_in[11];
  const float* attn_v = (const float*)d_in[12];
  const float* concat_W = (const float*)d_in[13];
  const float* concat_b = (const float*)d_in[14];
  const float* out_W = (const float*)d_in[15];
  const float* out_b = (const float*)d_in[16];
  const float* pgen_W = (const float*)d_in[17];
  const float* pgen_b = (const float*)d_in[18];
  const float* sig_W = (const float*)d_in[19];
  const float* sig_b = (const float*)d_in[20];

  float* out = (float*)d_out;
  float* ws = (float*)d_ws;
  float* gi     = ws;                  // 256*1536
  float* gh     = gi + 393216;         // 256*1536
  float* rnn    = gh + 393216;         // 256*512
  float* hW     = rnn + 131072;        // 256*512
  float* scores = hW + 131072;         // 256*400
  float* attnw  = scores + 102400;     // 256*400
  float* ctx    = attnw + 102400;      // 256*512
  float* cin    = ctx + 131072;        // 256*1024
  float* cout_  = cin + 262144;        // 256*512
  float* pgen   = cout_ + 131072;      // 256
  float* rowm   = pgen + 256;          // 256 (atomicMax keys)
  float* coef   = rowm + 256;          // 256 (unused, layout keep)
  float* logT   = coef + 256;          // 256 (unused, layout keep)
  unsigned short* Bhi = (unsigned short*)(logT + 256);   // packed We (single bf16 RNE): 32*16*64*8 shorts
  unsigned short* Blo = Bhi + 262144;                    // (unused since r27, layout keep)

  // prep: RNE-pack We (attn_W[:,512:1024]) -> fragment-ordered single-bf16 B for attn_mfma
  pack_rne<<<128, 256, 0, stream>>>(attn_W, 1024, 512, 512, Bhi);
  // zero scores (attn_mfma accumulates partials via atomicAdd) + rowm keys (0 == -inf key)
  hipMemsetAsync(scores, 0, 102400 * sizeof(float), stream);
  hipMemsetAsync(rowm, 0, 256 * sizeof(float), stream);
  // 1: merged GRU input+hidden GEMMs (192 concurrent blocks)
  gru_gemms<<<dim3(4, 48), 256, 0, stream>>>(input_step, last_hidden, W_ih, W_hh, b_ih, b_hh, gi, gh);
  // 2: gate combine -> rnn, hidden output, concat_in[:, :512]
  gru_combine<<<512, 256, 0, stream>>>(gi, gh, last_hidden, rnn, out + O_HID, cin);
  // 3: hW = rnn @ Wh.T + attn_b   (Wh = attn_W[:, :512])
  gemm_nt<0><<<dim3(4, 8), 256, 0, stream>>>(rnn, 512, attn_W, 1024, attn_b, hW, 512, 512, 512);
  // 4: fused MFMA energy GEMM -> partial scores (barrier-free direct-load, r28)
  attn_mfma<<<dim3(1600, 2), 256, 0, stream>>>(enc, Bhi, hW, attn_v, scores);
  // 5: softmax (applies mask) -> attn_w [B,S] + transposed output [S,B]
  softmax_k<<<256, 256, 0, stream>>>(scores, masks, attnw, out + O_ATT);
  // 6: fused context + pgen (1024 thr, 4-way s-split)
  context_pgen_k<<<256, 1024, 0, stream>>>(enc, attnw, last_hidden, input_step,
                                           pgen_W, pgen_b, ctx, cin, pgen);
  // 7: sig_hid
  sig_k<<<256, 64, 0, stream>>>(rnn, sig_W, sig_b, out + O_SIG);
  // 8: concat_out = gelu(cin @ concat_W.T + concat_b)
  gemm_nt<1><<<dim3(4, 8), 256, 0, stream>>>(cin, 1024, concat_W, 1024, concat_b, cout_, 512, 512, 1024);
  // 9: logits + per-row max (atomicMax keys), single-bf16 RNE (r26)
  logits_mfma<<<dim3(4, 197), 256, 0, stream>>>(cout_, out_W, out_b, out, (unsigned*)rowm);
  // 10: fused finale: exp+Z -> scatter -> log transform (analytic logT, no re-sum pass)
  finale_k<<<256, 1024, 0, stream>>>(out, pgen, (const unsigned*)rowm, ebev, attnw);
}

// Round 29
// 509.310 us; speedup vs baseline: 1.2452x; 1.2452x over previous
//
#include <hip/hip_runtime.h>
#include <hip/hip_bf16.h>
#include <math.h>

#define BB 256
#define SS 400
#define HH 512
#define EMBD 1024
#define VV 50257
#define VE 50357   // V + EXTRA
#define O_HID  12891392   // 256*50357
#define O_ATT  13022464   // O_HID + 256*512
#define O_SIG  13124864   // O_ATT + 400*256

typedef __attribute__((ext_vector_type(8))) short s8v;    // 8 bf16 (4 VGPR) MFMA A/B frag
typedef __attribute__((ext_vector_type(4))) float f4v;    // MFMA C/D frag

__device__ __forceinline__ float sigmoidf(float x) { return 1.f / (1.f + expf(-x)); }
__device__ __forceinline__ float geluf(float x) { return 0.5f * x * (1.f + erff(x * 0.70710678118654752f)); }

// round-to-nearest-even bf16 pack of TWO floats (r26/r27)
__device__ __forceinline__ unsigned rne2_pack(float x0, float x1) {
  unsigned u0 = __float_as_uint(x0), u1 = __float_as_uint(x1);
  unsigned r0 = (u0 + 0x7FFFu + ((u0 >> 16) & 1u)) >> 16;
  unsigned r1 = (u1 + 0x7FFFu + ((u1 >> 16) & 1u)) & 0xFFFF0000u;
  return r0 | r1;
}

// monotonic float<->unsigned key for atomicMax on floats (init key = 0 == -inf)
__device__ __forceinline__ unsigned fkey(float x) {
  unsigned u = __float_as_uint(x);
  return (u & 0x80000000u) ? ~u : (u | 0x80000000u);
}
__device__ __forceinline__ float fdecode(unsigned key) {
  unsigned u = (key & 0x80000000u) ? (key & 0x7FFFFFFFu) : ~key;
  return __uint_as_float(u);
}

// ---------------- generic NT GEMM: C[m,n] = act(sum_k A[m,k]*W[n,k] + bias[n]) ----------------
template<int ACT>
__global__ __launch_bounds__(256) void gemm_nt(const float* __restrict__ A, int lda,
                                               const float* __restrict__ W, int ldw,
                                               const float* __restrict__ bias,
                                               float* __restrict__ C, int ldc,
                                               int N, int K) {
  __shared__ __align__(16) float As[16][68];
  __shared__ __align__(16) float Ws[16][68];
  const int tid = threadIdx.x;
  const int m0 = blockIdx.x * 64, n0 = blockIdx.y * 64;
  const int tx = tid & 15, ty = tid >> 4;
  const int lr = tid >> 2;
  const int lk = (tid & 3) * 4;
  float acc[4][4] = {};
  for (int k0 = 0; k0 < K; k0 += 16) {
    float4 a4, w4;
    a4 = *(const float4*)(A + (size_t)(m0 + lr) * lda + k0 + lk);
    int wrow = n0 + lr;
    if (wrow < N) w4 = *(const float4*)(W + (size_t)wrow * ldw + k0 + lk);
    else          w4 = make_float4(0.f, 0.f, 0.f, 0.f);
    __syncthreads();
    As[lk + 0][lr] = a4.x; As[lk + 1][lr] = a4.y; As[lk + 2][lr] = a4.z; As[lk + 3][lr] = a4.w;
    Ws[lk + 0][lr] = w4.x; Ws[lk + 1][lr] = w4.y; Ws[lk + 2][lr] = w4.z; Ws[lk + 3][lr] = w4.w;
    __syncthreads();
#pragma unroll
    for (int k = 0; k < 16; ++k) {
      float4 av = *(const float4*)&As[k][ty * 4];
      float4 wv = *(const float4*)&Ws[k][tx * 4];
      float am[4] = {av.x, av.y, av.z, av.w};
      float wn[4] = {wv.x, wv.y, wv.z, wv.w};
#pragma unroll
      for (int i = 0; i < 4; ++i)
#pragma unroll
        for (int j = 0; j < 4; ++j) acc[i][j] += am[i] * wn[j];
    }
  }
#pragma unroll
  for (int i = 0; i < 4; ++i) {
    int row = m0 + ty * 4 + i;
#pragma unroll
    for (int j = 0; j < 4; ++j) {
      int col = n0 + tx * 4 + j;
      if (col < N) {
        float val = acc[i][j] + bias[col];
        if (ACT == 1) val = geluf(val);
        C[(size_t)row * ldc + col] = val;
      }
    }
  }
}

// ---------------- merged GRU input+hidden GEMMs: one launch, 192 concurrent blocks ----------------
__global__ __launch_bounds__(256) void gru_gemms(const float* __restrict__ input_step,
                                                 const float* __restrict__ last_hidden,
                                                 const float* __restrict__ W_ih,
                                                 const float* __restrict__ W_hh,
                                                 const float* __restrict__ b_ih,
                                                 const float* __restrict__ b_hh,
                                                 float* __restrict__ gi, float* __restrict__ gh) {
  __shared__ __align__(16) float As[16][68];
  __shared__ __align__(16) float Ws[16][68];
  const bool isGi = blockIdx.y < 24;
  const float* A = isGi ? input_step : last_hidden;
  const float* W = isGi ? W_ih : W_hh;
  const float* bias = isGi ? b_ih : b_hh;
  float* C = isGi ? gi : gh;
  const int lda = isGi ? 1024 : 512;
  const int K = isGi ? 1024 : 512;
  const int n0 = (isGi ? blockIdx.y : blockIdx.y - 24) * 64;
  const int m0 = blockIdx.x * 64;
  const int tid = threadIdx.x;
  const int tx = tid & 15, ty = tid >> 4;
  const int lr = tid >> 2;
  const int lk = (tid & 3) * 4;
  float acc[4][4] = {};
  for (int k0 = 0; k0 < K; k0 += 16) {
    float4 a4 = *(const float4*)(A + (size_t)(m0 + lr) * lda + k0 + lk);
    float4 w4 = *(const float4*)(W + (size_t)(n0 + lr) * lda + k0 + lk);   // ldw == lda here
    __syncthreads();
    As[lk + 0][lr] = a4.x; As[lk + 1][lr] = a4.y; As[lk + 2][lr] = a4.z; As[lk + 3][lr] = a4.w;
    Ws[lk + 0][lr] = w4.x; Ws[lk + 1][lr] = w4.y; Ws[lk + 2][lr] = w4.z; Ws[lk + 3][lr] = w4.w;
    __syncthreads();
#pragma unroll
    for (int k = 0; k < 16; ++k) {
      float4 av = *(const float4*)&As[k][ty * 4];
      float4 wv = *(const float4*)&Ws[k][tx * 4];
      float am[4] = {av.x, av.y, av.z, av.w};
      float wn[4] = {wv.x, wv.y, wv.z, wv.w};
#pragma unroll
      for (int i = 0; i < 4; ++i)
#pragma unroll
        for (int j = 0; j < 4; ++j) acc[i][j] += am[i] * wn[j];
    }
  }
#pragma unroll
  for (int i = 0; i < 4; ++i) {
    int row = m0 + ty * 4 + i;
#pragma unroll
    for (int j = 0; j < 4; ++j) {
      int col = n0 + tx * 4 + j;
      C[(size_t)row * 1536 + col] = acc[i][j] + bias[col];
    }
  }
}

// ---------------- GRU gate combine ----------------
__global__ __launch_bounds__(256) void gru_combine(const float* __restrict__ gi, const float* __restrict__ gh,
                                                   const float* __restrict__ hprev,
                                                   float* __restrict__ rnn, float* __restrict__ hid_out,
                                                   float* __restrict__ cin) {
  int idx = blockIdx.x * 256 + threadIdx.x;
  int b = idx >> 9, j = idx & 511;
  const float* gib = gi + (size_t)b * 1536;
  const float* ghb = gh + (size_t)b * 1536;
  float r = sigmoidf(gib[j] + ghb[j]);
  float z = sigmoidf(gib[512 + j] + ghb[512 + j]);
  float n = tanhf(gib[1024 + j] + r * ghb[1024 + j]);
  float h = hprev[idx];
  float o = (1.f - z) * n + z * h;
  rnn[idx] = o;
  hid_out[idx] = o;
  cin[(size_t)b * 1024 + j] = o;
}

// ---------------- pack a [rows][K=512] fp32 operand into MFMA-fragment-ordered single bf16 (RNE) ----
__global__ __launch_bounds__(256) void pack_rne(const float* __restrict__ src, int ld, int col0, int rows,
                                                unsigned short* __restrict__ d) {
  int idx = blockIdx.x * 256 + threadIdx.x;   // = (jb*16 + kb)*64 + l
  int l = idx & 63;
  int kb = (idx >> 6) & 15;
  int jb = idx >> 10;
  int j = jb * 16 + (l & 15);
  int k0 = kb * 32 + (l >> 4) * 8;
  float4 x0 = make_float4(0.f, 0.f, 0.f, 0.f), x1 = x0;
  if (j < rows) {
    const float* p = src + (size_t)j * ld + col0 + k0;
    x0 = *(const float4*)p;
    x1 = *(const float4*)(p + 4);
  }
  uint4 p = make_uint4(rne2_pack(x0.x, x0.y), rne2_pack(x0.z, x0.w),
                       rne2_pack(x1.x, x1.y), rne2_pack(x1.z, x1.w));
  *(uint4*)(d + (size_t)idx * 8) = p;
}

// ---------------- MFMA single-bf16 energy GEMM, high-occupancy (r29) ----------------------------
// r28 post-mortem: the constraint is latency -> need MORE RESIDENT WAVES, not fewer barriers.
// r29: r27's proven staged schedule shrunk to 32 rows x 128 cols per block (grid 3200x4),
// acc[2][2]+BH[2] => ~50 VGPR live; __launch_bounds__(256,8) forces the <=64-VGPR budget
// => 8 waves/SIMD (2x TLP). Barrier drains overlap across ~8 resident blocks/CU.
// enc (211MB) is L3-resident so the 4x jquad A-demand stays off HBM.
__global__ __launch_bounds__(256, 8) void attn_mfma(const float* __restrict__ enc,
                                                    const unsigned short* __restrict__ BP,
                                                    const float* __restrict__ hW,
                                                    const float* __restrict__ v,
                                                    float* __restrict__ scores) {
  __shared__ __align__(16) unsigned short AL[2 * 4 * 34 * 8];   // dbuf x 4 k-chunks x (32 rows + 2 pad)
  __shared__ float sredf[32][4];

  const int tid = threadIdx.x;
  const int R0 = blockIdx.x * 32;
  const int jquad = blockIdx.y;      // 0..3 -> 128-col group
  const int lane = tid & 63;
  const int w = tid >> 6;            // wave 0..3 -> 32-col group within the 128-col quarter
  const int jbBase = jquad * 8 + w * 2;   // fragment-blocks of 16 cols
  const int g = lane >> 4;           // k-chunk 0..3
  const int l16 = lane & 15;

  const int ar = tid >> 3;           // A staging row 0..31
  const int kc4 = tid & 7;           // float4 chunk 0..7 within the 32-float K-step
  const int akc = kc4 >> 1;          // 8-short LDS chunk
  const int ahalf = kc4 & 1;         // low/high half of the chunk
  const float* aptr = enc + (size_t)(R0 + ar) * 512 + kc4 * 4;

  const unsigned short* b0p = BP + lane * 8;   // fragment-packed: lane-contiguous

  f4v acc[2][2];
#pragma unroll
  for (int rt = 0; rt < 2; ++rt)
#pragma unroll
    for (int ct = 0; ct < 2; ++ct) acc[rt][ct] = (f4v){0.f, 0.f, 0.f, 0.f};

  // ---- prologue: stage A(0) into buf0; preload B(0) ----
  {
    float4 x = *(const float4*)(aptr);
    uint2 p = make_uint2(rne2_pack(x.x, x.y), rne2_pack(x.z, x.w));
    *(uint2*)&AL[((akc * 34 + ar) * 8) + ahalf * 4] = p;
  }
  s8v BH[2];
#pragma unroll
  for (int ct = 0; ct < 2; ++ct)
    BH[ct] = *(const s8v*)(b0p + ((jbBase + ct) * 16 + 0) * 512);
  __syncthreads();

  // ---- main K loop: 16 steps of 32 ----
  for (int t = 0; t < 16; ++t) {
    const int k0 = t * 32;
    float4 pa;
    if (t < 15) pa = *(const float4*)(aptr + k0 + 32);
    const int rb = ((t & 1) * 4 + g) * 34 + l16;
#pragma unroll
    for (int rt = 0; rt < 2; ++rt) {
      s8v a = *(const s8v*)&AL[(rb + rt * 16) * 8];
#pragma unroll
      for (int ct = 0; ct < 2; ++ct)
        acc[rt][ct] = __builtin_amdgcn_mfma_f32_16x16x32_bf16(a, BH[ct], acc[rt][ct], 0, 0, 0);
    }
    if (t < 15) {
#pragma unroll
      for (int ct = 0; ct < 2; ++ct)
        BH[ct] = *(const s8v*)(b0p + ((jbBase + ct) * 16 + (t + 1)) * 512);
      uint2 p = make_uint2(rne2_pack(pa.x, pa.y), rne2_pack(pa.z, pa.w));
      *(uint2*)&AL[((((t + 1) & 1) * 4 + akc) * 34 + ar) * 8 + ahalf * 4] = p;
    }
    __syncthreads();
  }

  // ---- epilogue: sp += tanh(acc + hW) * v over this wave's 32 cols ----
  float sp[2][4] = {};
#pragma unroll
  for (int ct = 0; ct < 2; ++ct) {
    int j = jquad * 128 + w * 32 + ct * 16 + l16;
    float vj = v[j];
    const float* hWj = hW + j;
#pragma unroll
    for (int rt = 0; rt < 2; ++rt) {
#pragma unroll
      for (int q = 0; q < 4; ++q) {
        int rl = rt * 16 + g * 4 + q;
        int b = (R0 + rl) & 255;
        float e = acc[rt][ct][q] + hWj[(size_t)b * 512];
        sp[rt][q] += tanhf(e) * vj;
      }
    }
  }

  // ---- reduce: sum over 16 lanes (cols) then over 4 waves; atomicAdd partial ----
#pragma unroll
  for (int rt = 0; rt < 2; ++rt)
#pragma unroll
    for (int q = 0; q < 4; ++q) {
      float s = sp[rt][q];
      s += __shfl_xor(s, 1); s += __shfl_xor(s, 2);
      s += __shfl_xor(s, 4); s += __shfl_xor(s, 8);
      if (l16 == 0) sredf[rt * 16 + g * 4 + q][w] = s;
    }
  __syncthreads();
  if (tid < 32) {
    float s = sredf[tid][0] + sredf[tid][1] + sredf[tid][2] + sredf[tid][3];
    int r = R0 + tid;
    int b = r & 255, si = r >> 8;
    atomicAdd(scores + b * 400 + si, s);
  }
}

// ---------------- MFMA single-bf16 logits GEMM + per-row max (atomicMax key) ----------------
// r26 proven version.
__global__ __launch_bounds__(256, 2) void logits_mfma(const float* __restrict__ A,
                                                      const float* __restrict__ W,
                                                      const float* __restrict__ bias,
                                                      float* __restrict__ out,
                                                      unsigned* __restrict__ rowmK) {
  __shared__ __align__(16) unsigned short AL[2 * 4 * 66 * 8];

  const int tid = threadIdx.x;
  const int R0 = blockIdx.x * 64;
  const int C0 = blockIdx.y * 256;
  const int lane = tid & 63;
  const int w = tid >> 6;
  const int g = lane >> 4;
  const int l16 = lane & 15;

  const int ar = tid >> 2;
  const int akc = tid & 3;
  const float* aptr = A + (size_t)(R0 + ar) * 512 + akc * 8;

  int jc[4]; bool jok[4];
#pragma unroll
  for (int ct = 0; ct < 4; ++ct) {
    jc[ct] = C0 + w * 64 + ct * 16 + l16;
    jok[ct] = jc[ct] < VV;
  }

  f4v acc[4][4];
#pragma unroll
  for (int rt = 0; rt < 4; ++rt)
#pragma unroll
    for (int ct = 0; ct < 4; ++ct) acc[rt][ct] = (f4v){0.f, 0.f, 0.f, 0.f};

  // prologue: stage A k-tile 0 (single bf16, RNE)
  {
    float4 pa0 = *(const float4*)(aptr);
    float4 pa1 = *(const float4*)(aptr + 4);
    uint4 p = make_uint4(rne2_pack(pa0.x, pa0.y), rne2_pack(pa0.z, pa0.w),
                         rne2_pack(pa1.x, pa1.y), rne2_pack(pa1.z, pa1.w));
    *(uint4*)&AL[(akc * 66 + ar) * 8] = p;
  }
  __syncthreads();

#pragma unroll 2
  for (int t = 0; t < 16; ++t) {
    const int k0 = t * 32;
    // B(t) load + RNE pack (head of step, r24 order)
    s8v Bf[4];
#pragma unroll
    for (int ct = 0; ct < 4; ++ct) {
      const float* wp = W + (size_t)(jok[ct] ? jc[ct] : 0) * 512 + k0 + g * 8;
      float4 b0 = *(const float4*)wp;
      float4 b1 = *(const float4*)(wp + 4);
      if (!jok[ct]) { b0 = make_float4(0.f, 0.f, 0.f, 0.f); b1 = b0; }
      uint4 pb = make_uint4(rne2_pack(b0.x, b0.y), rne2_pack(b0.z, b0.w),
                            rne2_pack(b1.x, b1.y), rne2_pack(b1.z, b1.w));
      Bf[ct] = *(s8v*)&pb;
    }
    // A(t+1) prefetch issue
    float4 pa0, pa1;
    if (t < 15) {
      pa0 = *(const float4*)(aptr + k0 + 32);
      pa1 = *(const float4*)(aptr + k0 + 36);
    }
    const int rb = ((t & 1) * 4 + g) * 66 + l16;
#pragma unroll
    for (int rt = 0; rt < 4; ++rt) {
      s8v a = *(const s8v*)&AL[(rb + rt * 16) * 8];
#pragma unroll
      for (int ct = 0; ct < 4; ++ct)
        acc[rt][ct] = __builtin_amdgcn_mfma_f32_16x16x32_bf16(a, Bf[ct], acc[rt][ct], 0, 0, 0);
    }
    // A(t+1) pack + write
    if (t < 15) {
      uint4 p = make_uint4(rne2_pack(pa0.x, pa0.y), rne2_pack(pa0.z, pa0.w),
                           rne2_pack(pa1.x, pa1.y), rne2_pack(pa1.z, pa1.w));
      *(uint4*)&AL[((((t + 1) & 1) * 4 + akc) * 66 + ar) * 8] = p;
    }
    __syncthreads();
  }

  // epilogue: bias + store (cols < VV only) + per-row max tracking
  float rmax[4][4];
#pragma unroll
  for (int rt = 0; rt < 4; ++rt)
#pragma unroll
    for (int q = 0; q < 4; ++q) rmax[rt][q] = -3e38f;
#pragma unroll
  for (int ct = 0; ct < 4; ++ct) {
    if (!jok[ct]) continue;
    float bj = bias[jc[ct]];
#pragma unroll
    for (int rt = 0; rt < 4; ++rt) {
      int row = R0 + rt * 16 + g * 4;
#pragma unroll
      for (int q = 0; q < 4; ++q) {
        float val = acc[rt][ct][q] + bj;
        out[(size_t)(row + q) * VE + jc[ct]] = val;
        rmax[rt][q] = fmaxf(rmax[rt][q], val);
      }
    }
  }
  // reduce row max: over 16 lanes (cols) then over 4 waves; atomicMax key
  float* redm = (float*)AL;  // [64][4]
#pragma unroll
  for (int rt = 0; rt < 4; ++rt)
#pragma unroll
    for (int q = 0; q < 4; ++q) {
      float mx = rmax[rt][q];
      mx = fmaxf(mx, __shfl_xor(mx, 1)); mx = fmaxf(mx, __shfl_xor(mx, 2));
      mx = fmaxf(mx, __shfl_xor(mx, 4)); mx = fmaxf(mx, __shfl_xor(mx, 8));
      if (l16 == 0) redm[(rt * 16 + g * 4 + q) * 4 + w] = mx;
    }
  __syncthreads();
  if (tid < 64) {
    float mx = fmaxf(fmaxf(redm[tid * 4 + 0], redm[tid * 4 + 1]),
                     fmaxf(redm[tid * 4 + 2], redm[tid * 4 + 3]));
    if (mx > -2e38f) atomicMax(rowmK + R0 + tid, fkey(mx));
  }
}

// ---------------- row softmax over S (applies mask), write [B,S] + transposed [S,B] ----------------
__global__ __launch_bounds__(256) void softmax_k(const float* __restrict__ scores,
                                                 const float* __restrict__ masks,
                                                 float* __restrict__ attnw, float* __restrict__ attnT) {
  int b = blockIdx.x, tid = threadIdx.x;
  __shared__ float red[4];
  float m = -3e38f;
  for (int s = tid; s < 400; s += 256) {
    float sc = (masks[b * 400 + s] > 0.f) ? scores[b * 400 + s] : -1e18f;
    m = fmaxf(m, sc);
  }
#pragma unroll
  for (int o = 32; o; o >>= 1) m = fmaxf(m, __shfl_xor(m, o));
  if ((tid & 63) == 0) red[tid >> 6] = m;
  __syncthreads();
  m = fmaxf(fmaxf(red[0], red[1]), fmaxf(red[2], red[3]));
  __syncthreads();
  float z = 0.f;
  for (int s = tid; s < 400; s += 256) {
    float sc = (masks[b * 400 + s] > 0.f) ? scores[b * 400 + s] : -1e18f;
    z += expf(sc - m);
  }
#pragma unroll
  for (int o = 32; o; o >>= 1) z += __shfl_xor(z, o);
  if ((tid & 63) == 0) red[tid >> 6] = z;
  __syncthreads();
  z = red[0] + red[1] + red[2] + red[3];
  float inv = 1.f / z;
  for (int s = tid; s < 400; s += 256) {
    float sc = (masks[b * 400 + s] > 0.f) ? scores[b * 400 + s] : -1e18f;
    float w = expf(sc - m) * inv;
    attnw[b * 400 + s] = w;
    attnT[s * 256 + b] = w;
  }
}

// ---------------- fused: context + pgen (1024 thr; ctx via 4-way s-split + LDS reduce) ----------
__global__ __launch_bounds__(1024) void context_pgen_k(const float* __restrict__ enc,
                                                       const float* __restrict__ attnw,
                                                       const float* __restrict__ hprev,
                                                       const float* __restrict__ emb,
                                                       const float* __restrict__ pW,
                                                       const float* __restrict__ pb,
                                                       float* __restrict__ ctx, float* __restrict__ cin,
                                                       float* __restrict__ pgen) {
  int b = blockIdx.x, tid = threadIdx.x;
  __shared__ float w[400];
  __shared__ float part[4][512];
  __shared__ float red[16];
  for (int s = tid; s < 400; s += 1024) w[s] = attnw[b * 400 + s];
  __syncthreads();
  const int h = (tid & 255) * 2;
  const int sq = tid >> 8;            // s-quarter 0..3
  const float* p = enc + (size_t)b * 512 + h;
  float cx = 0.f, cy = 0.f;
  const int s0 = sq * 100;
#pragma unroll 4
  for (int s = s0; s < s0 + 100; ++s) {
    float2 e = *(const float2*)(p + (size_t)s * 131072);
    cx += w[s] * e.x; cy += w[s] * e.y;
  }
  part[sq][h] = cx; part[sq][h + 1] = cy;
  __syncthreads();
  float vsum = 0.f;
  if (tid < 512) {
    vsum = part[0][tid] + part[1][tid] + part[2][tid] + part[3][tid];
    ctx[(size_t)b * 512 + tid] = vsum;
    cin[(size_t)b * 1024 + 512 + tid] = vsum;
  }
  __syncthreads();
  if (tid < 512) part[0][tid] = vsum;   // ctx snapshot for pgen dot
  __syncthreads();
  // pgen dot over [hprev(512) | ctx(512) | emb(1024)]
  float acc = 0.f;
#pragma unroll
  for (int kk = 0; kk < 2; ++kk) {
    int k = tid + kk * 1024;
    float x = (k < 512) ? hprev[(size_t)b * 512 + k]
            : (k < 1024) ? part[0][k - 512]
            : emb[(size_t)b * 1024 + k - 1024];
    acc += x * pW[k];
  }
#pragma unroll
  for (int o = 32; o; o >>= 1) acc += __shfl_xor(acc, o);
  if ((tid & 63) == 0) red[tid >> 6] = acc;
  __syncthreads();
  if (tid == 0) {
    float d = pb[0];
#pragma unroll
    for (int i = 0; i < 16; ++i) d += red[i];
    pgen[b] = sigmoidf(geluf(d));
  }
}

// ---------------- sig_hid = rnn . sig_W + b ----------------
__global__ void sig_k(const float* __restrict__ rnn, const float* __restrict__ sW,
                      const float* __restrict__ sb, float* __restrict__ outp) {
  int b = blockIdx.x, tid = threadIdx.x;
  float acc = 0.f;
  for (int k = tid; k < 512; k += 64) acc += rnn[(size_t)b * 512 + k] * sW[k];
#pragma unroll
  for (int o = 32; o; o >>= 1) acc += __shfl_xor(acc, o);
  if (tid == 0) outp[b] = acc + sb[0];
}

// ---------------- fused finale: exp+Z -> scatter -> log transform (analytic logT) --------------
// Post-scatter row sum is analytically 1: coef*sum(e) = pg, sum(attnD) = 1-pg.
// -> logT = log(1 + VE*1e-5) constant; the 51.5MB re-read summation pass is DELETED (r24).
__global__ __launch_bounds__(1024) void finale_k(float* __restrict__ out,
                                                 const float* __restrict__ pgen,
                                                 const unsigned* __restrict__ rowmK,
                                                 const int* __restrict__ ebev,
                                                 const float* __restrict__ attnw) {
  const int b = blockIdx.x, tid = threadIdx.x;
  float* row = out + (size_t)b * VE;
  __shared__ float red[16];
  __shared__ float shZ;
  const float m = fdecode(rowmK[b]);
  const float pg = pgen[b];
  // phase 1: e = exp(x - m) for j < VV, 0 elsewhere; write e; accumulate Z
  float z = 0.f;
  for (int j = tid * 4; j < 50356; j += 4096) {
    float4 x = *(const float4*)(row + j);
    float4 e;
    e.x = (j + 0 < VV) ? expf(x.x - m) : 0.f;
    e.y = (j + 1 < VV) ? expf(x.y - m) : 0.f;
    e.z = (j + 2 < VV) ? expf(x.z - m) : 0.f;
    e.w = (j + 3 < VV) ? expf(x.w - m) : 0.f;
    z += e.x + e.y + e.z + e.w;
    *(float4*)(row + j) = e;
  }
  if (tid == 0) row[50356] = 0.f;
#pragma unroll
  for (int o = 32; o; o >>= 1) z += __shfl_xor(z, o);
  if ((tid & 63) == 0) red[tid >> 6] = z;
  __syncthreads();
  if (tid == 0) {
    float t = 0.f;
#pragma unroll
    for (int i = 0; i < 16; ++i) t += red[i];
    shZ = t;
  }
  __syncthreads();
  const float coef = pg / shZ;
  // phase 2: scatter attnD/coef into own row (uncontended atomics)
  if (tid < 400) {
    int idx = ebev[tid * 256 + b];
    float wv = (1.f - pg) * attnw[b * 400 + tid] / coef;
    atomicAdd(row + idx, wv);
  }
  __syncthreads();
  // phase 3: final = log(coef*e' + 1e-5) - logT, with analytic logT (sum == 1 by construction)
  const float logT = logf(1.0f + (float)VE * 1e-5f);
  volatile const float* vrow = row;
  for (int j = tid; j < VE; j += 1024) {
    float e = vrow[j];
    row[j] = logf(coef * e + 1e-5f) - logT;
  }
}

extern "C" void kernel_launch(void* const* d_in, const int* in_sizes, int n_in,
                              void* d_out, int out_size, void* d_ws, size_t ws_size,
                              hipStream_t stream) {
  const float* input_step = (const float*)d_in[0];
  const float* last_hidden = (const float*)d_in[1];
  const float* enc = (const float*)d_in[2];
  const int*   ebev = (const int*)d_in[3];
  const float* masks = (const float*)d_in[5];
  const float* W_ih = (const float*)d_in[6];
  const float* W_hh = (const float*)d_in[7];
  const float* b_ih = (const float*)d_in[8];
  const float* b_hh = (const float*)d_in[9];
  const float* attn_W = (const float*)d_in[10];
  const float* attn_b = (const float*)d_in[11];
  const float* attn_v = (const float*)d_in[12];
  const float* concat_W = (const float*)d_in[13];
  const float* concat_b = (const float*)d_in[14];
  const float* out_W = (const float*)d_in[15];
  const float* out_b = (const float*)d_in[16];
  const float* pgen_W = (const float*)d_in[17];
  const float* pgen_b = (const float*)d_in[18];
  const float* sig_W = (const float*)d_in[19];
  const float* sig_b = (const float*)d_in[20];

  float* out = (float*)d_out;
  float* ws = (float*)d_ws;
  float* gi     = ws;                  // 256*1536
  float* gh     = gi + 393216;         // 256*1536
  float* rnn    = gh + 393216;         // 256*512
  float* hW     = rnn + 131072;        // 256*512
  float* scores = hW + 131072;         // 256*400
  float* attnw  = scores + 102400;     // 256*400
  float* ctx    = attnw + 102400;      // 256*512
  float* cin    = ctx + 131072;        // 256*1024
  float* cout_  = cin + 262144;        // 256*512
  float* pgen   = cout_ + 131072;      // 256
  float* rowm   = pgen + 256;          // 256 (atomicMax keys)
  float* coef   = rowm + 256;          // 256 (unused, layout keep)
  float* logT   = coef + 256;          // 256 (unused, layout keep)
  unsigned short* Bhi = (unsigned short*)(logT + 256);   // packed We (single bf16 RNE): 32*16*64*8 shorts
  unsigned short* Blo = Bhi + 262144;                    // (unused since r27, layout keep)

  // prep: RNE-pack We (attn_W[:,512:1024]) -> fragment-ordered single-bf16 B for attn_mfma
  pack_rne<<<128, 256, 0, stream>>>(attn_W, 1024, 512, 512, Bhi);
  // zero scores (attn_mfma accumulates partials via atomicAdd) + rowm keys (0 == -inf key)
  hipMemsetAsync(scores, 0, 102400 * sizeof(float), stream);
  hipMemsetAsync(rowm, 0, 256 * sizeof(float), stream);
  // 1: merged GRU input+hidden GEMMs (192 concurrent blocks)
  gru_gemms<<<dim3(4, 48), 256, 0, stream>>>(input_step, last_hidden, W_ih, W_hh, b_ih, b_hh, gi, gh);
  // 2: gate combine -> rnn, hidden output, concat_in[:, :512]
  gru_combine<<<512, 256, 0, stream>>>(gi, gh, last_hidden, rnn, out + O_HID, cin);
  // 3: hW = rnn @ Wh.T + attn_b   (Wh = attn_W[:, :512])
  gemm_nt<0><<<dim3(4, 8), 256, 0, stream>>>(rnn, 512, attn_W, 1024, attn_b, hW, 512, 512, 512);
  // 4: fused MFMA energy GEMM -> partial scores (high-occupancy 32x128 blocks, r29)
  attn_mfma<<<dim3(3200, 4), 256, 0, stream>>>(enc, Bhi, hW, attn_v, scores);
  // 5: softmax (applies mask) -> attn_w [B,S] + transposed output [S,B]
  softmax_k<<<256, 256, 0, stream>>>(scores, masks, attnw, out + O_ATT);
  // 6: fused context + pgen (1024 thr, 4-way s-split)
  context_pgen_k<<<256, 1024, 0, stream>>>(enc, attnw, last_hidden, input_step,
                                           pgen_W, pgen_b, ctx, cin, pgen);
  // 7: sig_hid
  sig_k<<<256, 64, 0, stream>>>(rnn, sig_W, sig_b, out + O_SIG);
  // 8: concat_out = gelu(cin @ concat_W.T + concat_b)
  gemm_nt<1><<<dim3(4, 8), 256, 0, stream>>>(cin, 1024, concat_W, 1024, concat_b, cout_, 512, 512, 1024);
  // 9: logits + per-row max (atomicMax keys), single-bf16 RNE (r26)
  logits_mfma<<<dim3(4, 197), 256, 0, stream>>>(cout_, out_W, out_b, out, (unsigned*)rowm);
  // 10: fused finale: exp+Z -> scatter -> log transform (analytic logT, no re-sum pass)
  finale_k<<<256, 1024, 0, stream>>>(out, pgen, (const unsigned*)rowm, ebev, attnw);
}